// Round 16
// baseline (118.570 us; speedup 1.0000x reference)
//
#include <hip/hip_runtime.h>
#include <math.h>

#define NDIMS 32
#define NANG 496          // 32*31/2
#define MPB 4             // matrices per gen_R block (128 threads)
#define TCOLS 256         // columns per apply block (64 lanes * 4)

typedef float f32x4 __attribute__((ext_vector_type(4)));
typedef float f32x2 __attribute__((ext_vector_type(2)));

// async 16B/lane global -> LDS (dest: wave-uniform base, HW adds lane*16;
// src: per-lane address)
__device__ __forceinline__ void load16_to_lds(const float* gsrc, float* ldst) {
    __builtin_amdgcn_global_load_lds(
        (const __attribute__((address_space(1))) void*)gsrc,
        (__attribute__((address_space(3))) void*)ldst,
        16, 0, 0);
}

// ---------------- Kernel 1: build R^T (mus folded) into workspace ----------
// RTbuf[m][k][i] = mus[m][i] * R[i][k]   ([k][i] layout)
__global__ __launch_bounds__(128)
void gen_R(const float* __restrict__ angles, const float* __restrict__ mus,
           float* __restrict__ RT)
{
    __shared__ float2 cs[MPB][NANG];      // 15872 B
    const int tid = threadIdx.x;
    const int m0  = blockIdx.x * MPB;

    for (int idx = tid; idx < MPB * NANG; idx += 128) {
        const int lm = idx / NANG, a = idx - lm * NANG;
        float sv, cv;
        sincosf(angles[(size_t)(m0 + lm) * NANG + a], &sv, &cv);
        cs[lm][a] = make_float2(cv, sv);
    }
    __syncthreads();

    const int lm = tid >> 5, j = tid & 31;   // lane j owns column j of mat[m]
    const int m  = m0 + lm;

    float r[NDIMS];
    #pragma unroll
    for (int i = 0; i < NDIMS; ++i) r[i] = (i == j) ? 1.0f : 0.0f;

    int sidx = 0;
    #pragma unroll
    for (int t = 0; t < NDIMS - 1; ++t) {
        #pragma unroll
        for (int b = t + 1; b < NDIMS; ++b) {
            const float2 v = cs[lm][sidx]; ++sidx;   // compile-time sidx
            const float c = v.x, sn = v.y;
            const float vt = r[t], vb = r[b];
            const float u  = sn * (vt + vb);
            r[t] = (c + sn) * vt - u;
            r[b] = (c - sn) * vb + u;
        }
    }

    // RT[m][k=j][i] = r[i] * mu[i]
    float* dst = RT + (size_t)m * (NDIMS * NDIMS) + (size_t)j * NDIMS;
    const float* mu = mus + (size_t)m * NDIMS;
    #pragma unroll
    for (int i = 0; i < NDIMS; i += 4) {
        f32x4 v;
        v.x = r[i + 0] * mu[i + 0];
        v.y = r[i + 1] * mu[i + 1];
        v.z = r[i + 2] * mu[i + 2];
        v.w = r[i + 3] * mu[i + 3];
        *reinterpret_cast<f32x4*>(dst + i) = v;
    }
}

// ---------------- Kernel 2: 512-thread, 4 rows x 4 cols per wave -----------
// R15 plateau (114.5us): VGPR 24, occ 77%, 3 LDS reads/k/wave. This round:
// wave tile 8x2 -> 4x4: same 16 FMA lanes per k (8 v_pk_fma_f32) but only
// 2 LDS reads (b128 xv lane-unique + b128 ra broadcast), stores widen to
// dwordx4, staging is one clean 1KB row per gload_lds, and 512-thread
// blocks at 36KB LDS give 4 blocks/CU x 8 waves = 32 waves/CU (100%).
// acc = 4 x f32x4 = 16 VGPR; (512,8) caps at 64, natural ~40, no spill.
__global__ __launch_bounds__(512, 8)
void apply_T3(const float* __restrict__ x, const float* __restrict__ RT,
              float* __restrict__ out, int S)
{
    __shared__ float rt[NDIMS * NDIMS];   // [k][i], 4 KB
    __shared__ float xt[NDIMS][TCOLS];    // [k][col], 32 KB

    const int tid  = threadIdx.x;
    const int m    = blockIdx.x;
    const int wid  = tid >> 6;            // wave id, 0..7
    const int lane = tid & 63;
    const int col0 = blockIdx.y * TCOLS;

    const float* __restrict__ xm = x   + (size_t)m * NDIMS * S + col0;
    float*       __restrict__ om = out + (size_t)m * NDIMS * S + col0;

    // stage R^T (4 KB): waves 0..3 issue one width-16 gload_lds each
    if (wid < 4)
        load16_to_lds(RT + (size_t)m * (NDIMS * NDIMS) + wid * 256 + lane * 4,
                      &rt[wid * 256]);

    // stage x tile (32 KB = 32 rows x 1 KB): wave wid stages rows
    // {wid*4 .. wid*4+3}, one full row per width-16 instr
    #pragma unroll
    for (int p = 0; p < 4; ++p) {
        const int k = wid * 4 + p;
        load16_to_lds(xm + (size_t)k * S + lane * 4, &xt[k][0]);
    }
    __syncthreads();   // drains vmcnt

    const int i0 = wid * 4;               // this wave's 4 output rows

    f32x4 acc[4];
    #pragma unroll
    for (int r = 0; r < 4; ++r) acc[r] = (f32x4)0.0f;

    #pragma unroll 2
    for (int k = 0; k < NDIMS; ++k) {
        const f32x4 xv = *reinterpret_cast<const f32x4*>(&xt[k][lane * 4]);    // lane-unique b128
        const f32x4 ra = *reinterpret_cast<const f32x4*>(&rt[k * NDIMS + i0]); // broadcast b128
        acc[0] += ra.x * xv;   // v_pk_fma_f32 x2 each
        acc[1] += ra.y * xv;
        acc[2] += ra.z * xv;
        acc[3] += ra.w * xv;
    }

    // stores: per row, wave writes 1 KB contiguous dwordx4; nontemporal
    #pragma unroll
    for (int r = 0; r < 4; ++r)
        __builtin_nontemporal_store(acc[r],
            reinterpret_cast<f32x4*>(om + (size_t)(i0 + r) * S + lane * 4));
}

// ---------------- Fallback: fused kernel (odd sizes / tiny ws) -------------
#define RT_STRIDE 36
__global__ __launch_bounds__(256, 4)
void soot_fused(const float* __restrict__ x, const float* __restrict__ angles,
                const float* __restrict__ mus, float* __restrict__ out, int S)
{
    __shared__ float2 cs[NANG];
    __shared__ float  RT[NDIMS * RT_STRIDE];
    const int tid = threadIdx.x;
    const int m   = blockIdx.x;

    for (int s0 = tid; s0 < NANG; s0 += 256) {
        float sv, cv;
        sincosf(angles[(size_t)m * NANG + s0], &sv, &cv);
        cs[s0] = make_float2(cv, sv);
    }
    __syncthreads();

    if (tid < NDIMS) {
        const int j = tid;
        float r[NDIMS];
        #pragma unroll
        for (int i = 0; i < NDIMS; ++i) r[i] = (i == j) ? 1.0f : 0.0f;
        int sidx = 0;
        #pragma unroll
        for (int t = 0; t < NDIMS - 1; ++t)
            #pragma unroll
            for (int b = t + 1; b < NDIMS; ++b) {
                const float2 v = cs[sidx]; ++sidx;
                const float c = v.x, sn = v.y;
                const float vt = r[t], vb = r[b];
                const float u  = sn * (vt + vb);
                r[t] = (c + sn) * vt - u;
                r[b] = (c - sn) * vb + u;
            }
        #pragma unroll
        for (int i = 0; i < NDIMS; ++i)
            RT[j * RT_STRIDE + i] = r[i] * mus[(size_t)m * NDIMS + i];
    }
    __syncthreads();

    for (int c0 = tid; c0 < S; c0 += 256) {
        float acc[NDIMS];
        #pragma unroll
        for (int i = 0; i < NDIMS; ++i) acc[i] = 0.f;
        #pragma unroll
        for (int k = 0; k < NDIMS; ++k) {
            const float xv = x[(size_t)m * NDIMS * S + (size_t)k * S + c0];
            #pragma unroll
            for (int i = 0; i < NDIMS; ++i)
                acc[i] = fmaf(RT[k * RT_STRIDE + i], xv, acc[i]);
        }
        #pragma unroll
        for (int i = 0; i < NDIMS; ++i)
            out[(size_t)m * NDIMS * S + (size_t)i * S + c0] = acc[i];
    }
}

extern "C" void kernel_launch(void* const* d_in, const int* in_sizes, int n_in,
                              void* d_out, int out_size, void* d_ws, size_t ws_size,
                              hipStream_t stream) {
    const float* x      = (const float*)d_in[0];
    const float* angles = (const float*)d_in[1];
    const float* mus    = (const float*)d_in[2];
    float* out          = (float*)d_out;

    const int M = in_sizes[1] / NANG;              // 1024
    const int S = in_sizes[0] / (M * NDIMS);       // 2048

    const size_t rt_bytes = (size_t)M * NDIMS * NDIMS * sizeof(float);  // 4 MB
    if (ws_size >= rt_bytes && (M % MPB) == 0 && (S % TCOLS) == 0) {
        float* RT = (float*)d_ws;
        gen_R<<<dim3(M / MPB), 128, 0, stream>>>(angles, mus, RT);
        dim3 grid(M, S / TCOLS);
        apply_T3<<<grid, 512, 0, stream>>>(x, RT, out, S);
    } else {
        soot_fused<<<dim3(M), 256, 0, stream>>>(x, angles, mus, out, S);
    }
}